// Round 4
// baseline (255.133 us; speedup 1.0000x reference)
//
#include <hip/hip_runtime.h>
#include <hip/hip_bf16.h>
#include <hip/hip_fp16.h>
#include <cstdint>

// ---------- types ----------
typedef unsigned short us;
typedef us   us8 __attribute__((ext_vector_type(8)));
typedef short s8v __attribute__((ext_vector_type(8)));   // 8 bf16 (4 VGPRs) MFMA A/B frag
typedef float f4v __attribute__((ext_vector_type(4)));   // MFMA C/D frag
typedef __fp16 pk2 __attribute__((ext_vector_type(2))); // cvt_pkrtz result type

// Problem constants (B=4, S=4096, D=1024 fixed by setup_inputs)
#define BB 4
#define SS 4096
#define DD 1024
#define MM (BB * SS)      // 16384
#define NN (2 * DD)       // 2048
#define KK DD             // 1024

// GEMM tiling
#define BM 128
#define BN 128
#define BK 64

// Scan chunking (128 chunks x 32 steps -> 1024 blocks in pass1/3 at 2 ch/thread)
#define CHUNK 32
#define NC (SS / CHUNK)   // 128
#define DP (DD / 2)       // 512 channel-pairs
#define BDP (BB * DP)     // 2048

// ---------- fp32 -> bf16 (RNE) ----------
__device__ inline us f2bf(float f) {
  unsigned u = __float_as_uint(f);
  u += 0x7fffu + ((u >> 16) & 1u);
  return (us)(u >> 16);
}

// one launch converts both x and W (x occupies blocks [0, 8192), W the rest)
__global__ __launch_bounds__(256) void cvt_both(const float* __restrict__ x,
                                                const float* __restrict__ W,
                                                us* __restrict__ xb,
                                                us* __restrict__ wb,
                                                long nx) {
  long i = ((long)blockIdx.x * 256 + threadIdx.x) * 8;
  const float* in;
  us* out;
  if (i < nx) { in = x + i; out = xb + i; }
  else        { in = W + (i - nx); out = wb + (i - nx); }
  const float4* p = (const float4*)in;
  float4 a = p[0], b = p[1];
  us8 o;
  o[0] = f2bf(a.x); o[1] = f2bf(a.y); o[2] = f2bf(a.z); o[3] = f2bf(a.w);
  o[4] = f2bf(b.x); o[5] = f2bf(b.y); o[6] = f2bf(b.z); o[7] = f2bf(b.w);
  *(us8*)out = o;
}

// ---------- async global->LDS, 16B per lane ----------
#define GLD16(g, l)                                                        \
  __builtin_amdgcn_global_load_lds(                                        \
      (const __attribute__((address_space(1))) void*)(g),                  \
      (__attribute__((address_space(3))) void*)(l), 16, 0, 0)

// ---------- gate math ----------
// h_t = coef*h_{t-1} + v ;  coef = sigmoid(-gate), v = sigmoid(gate)*g(hidden)
// g(x) = x+0.5 (x>=0) else sigmoid(x). Fast: v_exp + v_rcp (1 ulp), no divides.
__device__ inline void gate_cv(float hid, float gat, float& coef, float& v) {
  float e = __expf(gat);
  coef = __builtin_amdgcn_rcpf(1.0f + e);      // sigmoid(-gate)
  float z = 1.0f - coef;                        // sigmoid(gate), robust at e=inf
  float eh = __expf(hid < 0.0f ? hid : 0.0f);   // only meaningful on neg path
  float gneg = eh * __builtin_amdgcn_rcpf(1.0f + eh);  // eh<=1: safe
  float g = (hid >= 0.0f) ? (hid + 0.5f) : gneg;
  v = z * g;
}

// ---------- fused GEMM + gate epilogue ----------
// Each block covers 64 output channels d in [d0, d0+64). B(weight)-tile local
// row lr maps to W row perm(lr) = d0 + ((lr>>5)<<4) + (lr&15) + (((lr>>4)&1)<<10)
// -> wave wn's tile nt=even is hidden, nt=odd the SAME d's gate; each lane
// pairs hid/gate at identical (row,d), computes (coef,v), stores one half2.
__global__ __launch_bounds__(256) void gemm_fused(const us* __restrict__ A,
                                                  const us* __restrict__ B,
                                                  unsigned* __restrict__ cv) {
  __shared__ __align__(16) us As[BM * BK];
  __shared__ __align__(16) us Bs[BN * BK];

  const int tid  = threadIdx.x;
  const int lane = tid & 63;
  const int w    = tid >> 6;      // wave 0..3
  const int wm   = w & 1;         // 2x2 wave grid
  const int wn   = w >> 1;
  const long bm  = (long)blockIdx.x * BM;
  const int  d0  = blockIdx.y * 64;

  // staging: each global_load_lds covers 8 rows x 64 cols (1 KiB)
  const int srow = lane >> 3;                 // row within 8-row group
  const int sseg = (lane & 7) ^ srow;         // XOR-permuted source segment

  const int fr = lane & 15;
  const int fq = lane >> 4;                   // 0..3

  int aoff[4][2], boff[4][2];
#pragma unroll
  for (int mt = 0; mt < 4; ++mt) {
    int row = wm * 64 + mt * 16 + fr;
#pragma unroll
    for (int kk = 0; kk < 2; ++kk) {
      int seg = kk * 4 + fq;
      aoff[mt][kk] = row * BK + ((seg ^ (row & 7)) * 8);
    }
  }
#pragma unroll
  for (int nt = 0; nt < 4; ++nt) {
    int row = wn * 64 + nt * 16 + fr;
#pragma unroll
    for (int kk = 0; kk < 2; ++kk) {
      int seg = kk * 4 + fq;
      boff[nt][kk] = row * BK + ((seg ^ (row & 7)) * 8);
    }
  }

  f4v acc[4][4] = {};

  const us* Ap[4];
  const us* Bp[4];
#pragma unroll
  for (int i = 0; i < 4; ++i) {
    int lr = w * 32 + i * 8 + srow;           // local tile row
    Ap[i] = A + (bm + lr) * (long)KK + sseg * 8;
    int wrow = d0 + ((lr >> 5) << 4) + (lr & 15) + (((lr >> 4) & 1) << 10);
    Bp[i] = B + (long)wrow * KK + sseg * 8;
  }

  for (int kt = 0; kt < KK / BK; ++kt) {
    const int k0 = kt * BK;
    __syncthreads();   // previous tile's reads done before overwrite
#pragma unroll
    for (int i = 0; i < 4; ++i) {
      GLD16(Ap[i] + k0, &As[(w * 32 + i * 8) * BK]);
      GLD16(Bp[i] + k0, &Bs[(w * 32 + i * 8) * BK]);
    }
    __syncthreads();   // staging visible

#pragma unroll
    for (int kk = 0; kk < 2; ++kk) {
      s8v af[4], bf[4];
#pragma unroll
      for (int mt = 0; mt < 4; ++mt) af[mt] = *(const s8v*)&As[aoff[mt][kk]];
#pragma unroll
      for (int nt = 0; nt < 4; ++nt) bf[nt] = *(const s8v*)&Bs[boff[nt][kk]];
#pragma unroll
      for (int mt = 0; mt < 4; ++mt)
#pragma unroll
        for (int nt = 0; nt < 4; ++nt)
          acc[mt][nt] = __builtin_amdgcn_mfma_f32_16x16x32_bf16(
              af[mt], bf[nt], acc[mt][nt], 0, 0, 0);
    }
  }

  // epilogue: C/D row = fq*4 + r, col = fr (m89 layout); pair (nt=2p, 2p+1)
#pragma unroll
  for (int mt = 0; mt < 4; ++mt) {
    long rb = bm + wm * 64 + mt * 16 + fq * 4;
#pragma unroll
    for (int p = 0; p < 2; ++p) {
      int d = d0 + (wn * 2 + p) * 16 + fr;
      f4v hv = acc[mt][2 * p];
      f4v gv = acc[mt][2 * p + 1];
#pragma unroll
      for (int r = 0; r < 4; ++r) {
        float coef, v;
        gate_cv(hv[r], gv[r], coef, v);
        pk2 pk = __builtin_amdgcn_cvt_pkrtz(coef, v);   // one v_cvt_pkrtz
        cv[(rb + r) * (size_t)DD + d] = __builtin_bit_cast(unsigned, pk);
      }
    }
  }
}

// pass1: per (b, d-pair, chunk): coeff-products and chunk-local h (h_in = 0)
__global__ __launch_bounds__(256) void scan_pass1(const uint2* __restrict__ cv,
                                                  float2* __restrict__ cp,
                                                  float2* __restrict__ ch) {
  const int dp = blockIdx.x * 256 + threadIdx.x;  // 0..511 channel pair
  const int c = blockIdx.y;
  const int b = blockIdx.z;
  const uint2* base = cv + ((size_t)b * SS + (size_t)c * CHUNK) * DP + dp;
  float P0 = 1.0f, h0 = 0.0f, P1 = 1.0f, h1 = 0.0f;
#pragma unroll 8
  for (int t = 0; t < CHUNK; ++t) {
    uint2 u = base[(size_t)t * DP];
    __half2 a = *(__half2*)&u.x;
    __half2 bq = *(__half2*)&u.y;
    float c0 = __half2float(a.x), v0 = __half2float(a.y);
    float c1 = __half2float(bq.x), v1 = __half2float(bq.y);
    h0 = fmaf(c0, h0, v0);  P0 *= c0;
    h1 = fmaf(c1, h1, v1);  P1 *= c1;
  }
  const int idx = c * BDP + b * DP + dp;          // [c][b][dp] coalesced for pass2
  cp[idx] = make_float2(P0, P1);
  ch[idx] = make_float2(h0, h1);
}

// pass2: serial scan over NC chunk summaries per sequence; 2048 threads
__global__ __launch_bounds__(256) void scan_pass2(const float2* __restrict__ cp,
                                                  const float2* __restrict__ ch,
                                                  float2* __restrict__ carry) {
  const int bdp = blockIdx.x * 256 + threadIdx.x; // 0..2047
  float h0 = 0.0f, h1 = 0.0f;
  for (int c = 0; c < NC; ++c) {
    carry[c * BDP + bdp] = make_float2(h0, h1);   // carry INTO chunk c
    float2 P = cp[c * BDP + bdp];
    float2 H = ch[c * BDP + bdp];
    h0 = fmaf(P.x, h0, H.x);
    h1 = fmaf(P.y, h1, H.y);
  }
}

// pass3: re-run each chunk with the correct carry-in, write out (float2)
__global__ __launch_bounds__(256) void scan_pass3(const uint2* __restrict__ cv,
                                                  const float2* __restrict__ carry,
                                                  float2* __restrict__ out) {
  const int dp = blockIdx.x * 256 + threadIdx.x;
  const int c = blockIdx.y;
  const int b = blockIdx.z;
  const uint2* base = cv + ((size_t)b * SS + (size_t)c * CHUNK) * DP + dp;
  float2* obase = out + ((size_t)b * SS + (size_t)c * CHUNK) * DP + dp;
  float2 hc = carry[c * BDP + b * DP + dp];
  float h0 = hc.x, h1 = hc.y;
#pragma unroll 8
  for (int t = 0; t < CHUNK; ++t) {
    uint2 u = base[(size_t)t * DP];
    __half2 a = *(__half2*)&u.x;
    __half2 bq = *(__half2*)&u.y;
    h0 = fmaf(__half2float(a.x), h0, __half2float(a.y));
    h1 = fmaf(__half2float(bq.x), h1, __half2float(bq.y));
    obase[(size_t)t * DP] = make_float2(h0, h1);
  }
}

// ---------- launch ----------
extern "C" void kernel_launch(void* const* d_in, const int* in_sizes, int n_in,
                              void* d_out, int out_size, void* d_ws, size_t ws_size,
                              hipStream_t stream) {
  const float* x = (const float*)d_in[0];   // [4,4096,1024] fp32
  const float* W = (const float*)d_in[1];   // [2048,1024]  fp32
  float2* out = (float2*)d_out;             // [4,4096,1024] fp32

  const long nx = (long)MM * KK;            // 16,777,216
  const long nw = (long)NN * KK;            //  2,097,152

  // workspace layout (~106 MiB total)
  char* ws = (char*)d_ws;
  unsigned* cv = (unsigned*)ws;      ws += (size_t)MM * DD * sizeof(unsigned); // 64 MiB
  us* xb = (us*)ws;                  ws += (size_t)nx * sizeof(us);            // 32 MiB
  us* wb = (us*)ws;                  ws += (size_t)nw * sizeof(us);            //  4 MiB
  float2* cp = (float2*)ws;          ws += (size_t)NC * BDP * sizeof(float2);  //  2 MiB
  float2* chh = (float2*)ws;         ws += (size_t)NC * BDP * sizeof(float2);  //  2 MiB
  float2* carry = (float2*)ws;       ws += (size_t)NC * BDP * sizeof(float2);  //  2 MiB

  cvt_both<<<(int)((nx + nw) / 8 / 256), 256, 0, stream>>>(x, W, xb, wb, nx);

  gemm_fused<<<dim3(MM / BM, DD / 64), 256, 0, stream>>>(xb, wb, cv); // 128 x 16

  scan_pass1<<<dim3(DP / 256, NC, BB), 256, 0, stream>>>((const uint2*)cv, cp, chh);
  scan_pass2<<<dim3(BDP / 256), 256, 0, stream>>>(cp, chh, carry);
  scan_pass3<<<dim3(DP / 256, NC, BB), 256, 0, stream>>>((const uint2*)cv, carry, out);
}

// Round 5
// 234.242 us; speedup vs baseline: 1.0892x; 1.0892x over previous
//
#include <hip/hip_runtime.h>
#include <hip/hip_bf16.h>
#include <hip/hip_fp16.h>
#include <cstdint>

// ---------- types ----------
typedef unsigned short us;
typedef us   us8 __attribute__((ext_vector_type(8)));
typedef short s8v __attribute__((ext_vector_type(8)));   // 8 bf16 (4 VGPRs) MFMA A/B frag
typedef float f4v __attribute__((ext_vector_type(4)));   // MFMA C/D frag
typedef __fp16 pk2 __attribute__((ext_vector_type(2))); // cvt_pkrtz result type

// Problem constants (B=4, S=4096, D=1024 fixed by setup_inputs)
#define BB 4
#define SS 4096
#define DD 1024
#define MM (BB * SS)      // 16384
#define NN (2 * DD)       // 2048
#define KK DD             // 1024

// GEMM tiling
#define BM 128
#define BN 128
#define BK 64

// Scan chunking: 32-step chunks; one 128-row GEMM tile = exactly 4 chunks
#define CHUNK 32
#define NC (SS / CHUNK)   // 128
#define BDD (BB * DD)     // 4096 sequences
#define DP (DD / 2)       // 512 channel-pairs (pass3 vectorization)

// ---------- fp32 -> bf16 (RNE) ----------
__device__ inline us f2bf(float f) {
  unsigned u = __float_as_uint(f);
  u += 0x7fffu + ((u >> 16) & 1u);
  return (us)(u >> 16);
}

// one launch converts both x and W (x occupies blocks [0, 8192), W the rest)
__global__ __launch_bounds__(256) void cvt_both(const float* __restrict__ x,
                                                const float* __restrict__ W,
                                                us* __restrict__ xb,
                                                us* __restrict__ wb,
                                                long nx) {
  long i = ((long)blockIdx.x * 256 + threadIdx.x) * 8;
  const float* in;
  us* out;
  if (i < nx) { in = x + i; out = xb + i; }
  else        { in = W + (i - nx); out = wb + (i - nx); }
  const float4* p = (const float4*)in;
  float4 a = p[0], b = p[1];
  us8 o;
  o[0] = f2bf(a.x); o[1] = f2bf(a.y); o[2] = f2bf(a.z); o[3] = f2bf(a.w);
  o[4] = f2bf(b.x); o[5] = f2bf(b.y); o[6] = f2bf(b.z); o[7] = f2bf(b.w);
  *(us8*)out = o;
}

// ---------- async global->LDS, 16B per lane ----------
#define GLD16(g, l)                                                        \
  __builtin_amdgcn_global_load_lds(                                        \
      (const __attribute__((address_space(1))) void*)(g),                  \
      (__attribute__((address_space(3))) void*)(l), 16, 0, 0)

// ---------- gate math ----------
// h_t = coef*h_{t-1} + v ;  coef = sigmoid(-gate), v = sigmoid(gate)*g(hidden)
// g(x) = x+0.5 (x>=0) else sigmoid(x). Fast: v_exp + v_rcp (1 ulp), no divides.
__device__ inline void gate_cv(float hid, float gat, float& coef, float& v) {
  float e = __expf(gat);
  coef = __builtin_amdgcn_rcpf(1.0f + e);      // sigmoid(-gate)
  float z = 1.0f - coef;                        // sigmoid(gate), robust at e=inf
  float eh = __expf(hid < 0.0f ? hid : 0.0f);   // only meaningful on neg path
  float gneg = eh * __builtin_amdgcn_rcpf(1.0f + eh);  // eh<=1: safe
  float g = (hid >= 0.0f) ? (hid + 0.5f) : gneg;
  v = z * g;
}

// ---------- fused GEMM + gate epilogue + chunk-local scan (pass1) ----------
// Block covers 128 consecutive rows (= 4 chunks of 32 t's within one batch b)
// x 64 output channels [d0, d0+64). W-row permutation pairs hid/gate per lane
// (see R2 comment). Epilogue: (coef,v)->half2 into a 32 KB LDS transpose
// (reusing the staging LDS), then (1) coalesced uint4 row-writes of cv,
// (2) per-thread 32-step scan giving chunk coeff-product P and local h.
__global__ __launch_bounds__(256) void gemm_fused(const us* __restrict__ A,
                                                  const us* __restrict__ B,
                                                  unsigned* __restrict__ cv,
                                                  float* __restrict__ cp,
                                                  float* __restrict__ ch) {
  __shared__ __align__(16) us smem[BM * BK + BN * BK];  // 32 KB
  us* As = smem;
  us* Bs = smem + BM * BK;
  unsigned* T = (unsigned*)smem;    // epilogue reuse: [128 rows][64 d] uint

  const int tid  = threadIdx.x;
  const int lane = tid & 63;
  const int w    = tid >> 6;      // wave 0..3
  const int wm   = w & 1;         // 2x2 wave grid
  const int wn   = w >> 1;
  const long bm  = (long)blockIdx.x * BM;
  const int  d0  = blockIdx.y * 64;

  // staging: each global_load_lds covers 8 rows x 64 cols (1 KiB)
  const int srow = lane >> 3;                 // row within 8-row group
  const int sseg = (lane & 7) ^ srow;         // XOR-permuted source segment

  const int fr = lane & 15;
  const int fq = lane >> 4;                   // 0..3

  int aoff[4][2], boff[4][2];
#pragma unroll
  for (int mt = 0; mt < 4; ++mt) {
    int row = wm * 64 + mt * 16 + fr;
#pragma unroll
    for (int kk = 0; kk < 2; ++kk) {
      int seg = kk * 4 + fq;
      aoff[mt][kk] = row * BK + ((seg ^ (row & 7)) * 8);
    }
  }
#pragma unroll
  for (int nt = 0; nt < 4; ++nt) {
    int row = wn * 64 + nt * 16 + fr;
#pragma unroll
    for (int kk = 0; kk < 2; ++kk) {
      int seg = kk * 4 + fq;
      boff[nt][kk] = row * BK + ((seg ^ (row & 7)) * 8);
    }
  }

  f4v acc[4][4] = {};

  const us* Ap[4];
  const us* Bp[4];
#pragma unroll
  for (int i = 0; i < 4; ++i) {
    int lr = w * 32 + i * 8 + srow;           // local tile row
    Ap[i] = A + (bm + lr) * (long)KK + sseg * 8;
    int wrow = d0 + ((lr >> 5) << 4) + (lr & 15) + (((lr >> 4) & 1) << 10);
    Bp[i] = B + (long)wrow * KK + sseg * 8;
  }

  for (int kt = 0; kt < KK / BK; ++kt) {
    __syncthreads();   // previous tile's reads done before overwrite
#pragma unroll
    for (int i = 0; i < 4; ++i) {
      GLD16(Ap[i], &As[(w * 32 + i * 8) * BK]);
      GLD16(Bp[i], &Bs[(w * 32 + i * 8) * BK]);
      Ap[i] += BK;
      Bp[i] += BK;
    }
    __syncthreads();   // staging visible

#pragma unroll
    for (int kk = 0; kk < 2; ++kk) {
      s8v af[4], bf[4];
#pragma unroll
      for (int mt = 0; mt < 4; ++mt) af[mt] = *(const s8v*)&As[aoff[mt][kk]];
#pragma unroll
      for (int nt = 0; nt < 4; ++nt) bf[nt] = *(const s8v*)&Bs[boff[nt][kk]];
#pragma unroll
      for (int mt = 0; mt < 4; ++mt)
#pragma unroll
        for (int nt = 0; nt < 4; ++nt)
          acc[mt][nt] = __builtin_amdgcn_mfma_f32_16x16x32_bf16(
              af[mt], bf[nt], acc[mt][nt], 0, 0, 0);
    }
  }

  // ---- epilogue ----
  __syncthreads();   // all waves done with As/Bs; reuse LDS as T
  // C/D row = fq*4 + r, col = fr (m89 layout); hid/gate pair = (nt=2p, 2p+1)
#pragma unroll
  for (int mt = 0; mt < 4; ++mt) {
    int lr0 = wm * 64 + mt * 16 + fq * 4;     // local row base
#pragma unroll
    for (int p = 0; p < 2; ++p) {
      int ld = (wn * 2 + p) * 16 + fr;        // local d
      f4v hv = acc[mt][2 * p];
      f4v gv = acc[mt][2 * p + 1];
#pragma unroll
      for (int r = 0; r < 4; ++r) {
        float coef, v;
        gate_cv(hv[r], gv[r], coef, v);
        pk2 pk = __builtin_amdgcn_cvt_pkrtz(coef, v);   // (lo=coef, hi=v)
        T[(lr0 + r) * 64 + ld] = __builtin_bit_cast(unsigned, pk);
      }
    }
  }
  __syncthreads();   // transpose complete

  // (1) coalesced cv writes: 2048 uint4 chunks (128 rows x 16), 8 per thread
#pragma unroll
  for (int j = 0; j < 8; ++j) {
    int chunk = j * 256 + tid;
    int row = chunk >> 4;                     // 0..127
    int q   = chunk & 15;                     // 16B chunk within row
    uint4 val = *(const uint4*)&T[row * 64 + q * 4];
    *(uint4*)(cv + (size_t)(bm + row) * DD + d0 + q * 4) = val;
  }

  // (2) chunk-local scan: thread -> (local chunk c = tid>>6, d = tid&63)
  {
    const int d = tid & 63;
    const int c = tid >> 6;                   // 0..3
    float P = 1.0f, h = 0.0f;
#pragma unroll
    for (int i = 0; i < CHUNK; ++i) {
      unsigned u = T[(c * CHUNK + i) * 64 + d];
      __half2 hv = *(__half2*)&u;
      float cf = __half2float(hv.x);
      h = fmaf(cf, h, __half2float(hv.y));
      P *= cf;
    }
    const int b  = (int)(bm / SS);
    const int cg = (int)((bm % SS) / CHUNK) + c;   // global chunk 0..127
    const int idx = cg * BDD + b * DD + d0 + d;    // [chunk][b][d]
    cp[idx] = P;
    ch[idx] = h;
  }
}

// pass2: serial scan over NC chunk summaries per sequence; 4096 threads
__global__ __launch_bounds__(256) void scan_pass2(const float* __restrict__ cp,
                                                  const float* __restrict__ ch,
                                                  float* __restrict__ carry) {
  const int bd = blockIdx.x * 256 + threadIdx.x;  // 0..4095
  float h = 0.0f;
  for (int c = 0; c < NC; ++c) {
    carry[c * BDD + bd] = h;                      // carry INTO chunk c
    h = fmaf(cp[c * BDD + bd], h, ch[c * BDD + bd]);
  }
}

// pass3: re-run each chunk with the correct carry-in, write out (float2)
__global__ __launch_bounds__(256) void scan_pass3(const uint2* __restrict__ cv,
                                                  const float* __restrict__ carry,
                                                  float2* __restrict__ out) {
  const int dp = blockIdx.x * 256 + threadIdx.x;  // 0..511 channel pair
  const int c = blockIdx.y;
  const int b = blockIdx.z;
  const uint2* base = cv + ((size_t)b * SS + (size_t)c * CHUNK) * DP + dp;
  float2* obase = out + ((size_t)b * SS + (size_t)c * CHUNK) * DP + dp;
  float2 hc = *(const float2*)&carry[c * BDD + b * DD + 2 * dp];
  float h0 = hc.x, h1 = hc.y;
#pragma unroll 8
  for (int t = 0; t < CHUNK; ++t) {
    uint2 u = base[(size_t)t * DP];
    __half2 a = *(__half2*)&u.x;
    __half2 bq = *(__half2*)&u.y;
    h0 = fmaf(__half2float(a.x), h0, __half2float(a.y));
    h1 = fmaf(__half2float(bq.x), h1, __half2float(bq.y));
    obase[(size_t)t * DP] = make_float2(h0, h1);
  }
}

// ---------- launch ----------
extern "C" void kernel_launch(void* const* d_in, const int* in_sizes, int n_in,
                              void* d_out, int out_size, void* d_ws, size_t ws_size,
                              hipStream_t stream) {
  const float* x = (const float*)d_in[0];   // [4,4096,1024] fp32
  const float* W = (const float*)d_in[1];   // [2048,1024]  fp32
  float2* out = (float2*)d_out;             // [4,4096,1024] fp32

  const long nx = (long)MM * KK;            // 16,777,216
  const long nw = (long)NN * KK;            //  2,097,152

  // workspace layout (~106 MiB total)
  char* ws = (char*)d_ws;
  unsigned* cv = (unsigned*)ws;      ws += (size_t)MM * DD * sizeof(unsigned); // 64 MiB
  us* xb = (us*)ws;                  ws += (size_t)nx * sizeof(us);            // 32 MiB
  us* wb = (us*)ws;                  ws += (size_t)nw * sizeof(us);            //  4 MiB
  float* cp = (float*)ws;            ws += (size_t)NC * BDD * sizeof(float);   //  2 MiB
  float* chh = (float*)ws;           ws += (size_t)NC * BDD * sizeof(float);   //  2 MiB
  float* carry = (float*)ws;         ws += (size_t)NC * BDD * sizeof(float);   //  2 MiB

  cvt_both<<<(int)((nx + nw) / 8 / 256), 256, 0, stream>>>(x, W, xb, wb, nx);

  gemm_fused<<<dim3(MM / BM, DD / 64), 256, 0, stream>>>(xb, wb, cv, cp, chh);

  scan_pass2<<<dim3(BDD / 256), 256, 0, stream>>>(cp, chh, carry);
  scan_pass3<<<dim3(DP / 256, NC, BB), 256, 0, stream>>>((const uint2*)cv, carry, out);
}